// Round 3
// baseline (742.814 us; speedup 1.0000x reference)
//
#include <hip/hip_runtime.h>
#include <hip/hip_bf16.h>

typedef __bf16 bf16x8 __attribute__((ext_vector_type(8)));
typedef float f32x4 __attribute__((ext_vector_type(4)));

#define NTOT   131072
#define NODES_PER_AUDIO 2048
#define NAUDIO 64
#define POOL_CHUNKS 16
#define CHUNK_NODES (NODES_PER_AUDIO / POOL_CHUNKS)   // 128

#define SBAR __builtin_amdgcn_sched_barrier(0)
#define AS1 __attribute__((address_space(1)))
#define AS3 __attribute__((address_space(3)))
#define GLL(SRC, DST) __builtin_amdgcn_global_load_lds( \
    (const AS1 void*)(SRC), (AS3 void*)(DST), 16, 0, 0)

// ---------------------------------------------------------------------------
// dtype detection (flag=1 -> bf16 inputs, flag=0 -> f32)
// ---------------------------------------------------------------------------
__global__ __launch_bounds__(256)
void detect_dtype(const unsigned* __restrict__ x, int* __restrict__ flag)
{
    const int tid = threadIdx.x;
    int cnt = 0;
    for (int i = tid; i < 4096; i += 256) {
        unsigned e = (x[i] >> 7) & 0xFF;
        cnt += (e >= 100 && e <= 145) ? 1 : 0;
    }
    __shared__ int red[256];
    red[tid] = cnt; __syncthreads();
    for (int s = 128; s > 0; s >>= 1) {
        if (tid < s) red[tid] += red[tid + s];
        __syncthreads();
    }
    if (tid == 0) *flag = (red[0] > 3000) ? 1 : 0;
}

struct W14 { const void* s[14]; int n[14]; int off[14]; };

__global__ __launch_bounds__(256)
void convert_weights(W14 w, const int* __restrict__ flag, __bf16* __restrict__ wb)
{
    const int f = *flag;
    const int stride = gridDim.x * 256;
    for (int t = 0; t < 14; t++) {
        const void* src = w.s[t];
        __bf16* d = wb + w.off[t];
        for (int i = blockIdx.x * 256 + threadIdx.x; i < w.n[t]; i += stride)
            d[i] = f ? ((const __bf16*)src)[i] : (__bf16)((const float*)src)[i];
    }
}

// f32 -> bf16 conversion of x (no-op when input already bf16)
__global__ __launch_bounds__(256)
void convert_x(const float4* __restrict__ xf, __bf16* __restrict__ xb,
               const int* __restrict__ flag)
{
    if (*flag) return;
    const unsigned stride = gridDim.x * 256;
    for (unsigned i = blockIdx.x * 256 + threadIdx.x; i < 16777216u; i += stride) {
        float4 v = xf[i];
        __bf16 t[4] = {(__bf16)v.x, (__bf16)v.y, (__bf16)v.z, (__bf16)v.w};
        *(int2*)&xb[(size_t)i * 4] = *(int2*)t;
    }
}

// ---------------------------------------------------------------------------
// Pipelined GEMM: C[M,Nc] = A[M,K] @ W[Nc,K]^T, 128x128 tile, 4 waves, BK=64.
// Double-buffered LDS (64 KB -> 2 blocks/CU), counted vmcnt(8) (next tile's
// loads stay in flight ACROSS barriers; never a mid-loop drain), T2 chunk
// swizzle (LDS slot s of row r holds global chunk s^(r&7); linear GLL dest,
// inverse-swizzled source, swizzled ds_read -> conflict-free b128 reads),
// setprio around MFMA. XCD-aware block swizzle as round 0.
// Per-step schedule:
//   ds_read 16 frags (buf p) -> lgkm(0) -> barrier -> STG(s+2 -> buf p)
//   -> 32 MFMA -> vmcnt(8) [= stage(s+1) landed] -> barrier
// ---------------------------------------------------------------------------
#define STG(S, P) do {                                                  \
    const int _k0 = (S) * 64;                                           \
    _Pragma("unroll")                                                   \
    for (int _i = 0; _i < 4; _i++)                                      \
        GLL(ap[_i] + _k0, &As[(P) * 8192 + ld[_i]]);                    \
    _Pragma("unroll")                                                   \
    for (int _i = 0; _i < 4; _i++)                                      \
        GLL(bp[_i] + _k0, &Bs[(P) * 8192 + ld[_i]]);                    \
} while (0)

template<int NX>
__global__ __launch_bounds__(256, 2)
void gemm_pipe(const void* __restrict__ Araw, const __bf16* __restrict__ Aconv,
               const __bf16* __restrict__ W, __bf16* __restrict__ C,
               int M, int K, int Nc, const int* __restrict__ flagp)
{
    __shared__ __align__(16) __bf16 As[2 * 128 * 64];
    __shared__ __align__(16) __bf16 Bs[2 * 128 * 64];

    const __bf16* A = (const __bf16*)Araw;
    if (!*flagp) A = Aconv;

    // XCD swizzle: xcd = bid&7 owns a contiguous y-stripe; NX col-tiles of a
    // row adjacent in time -> A row crosses HBM once. ny % 8 == 0 for both uses.
    const int nb  = gridDim.x;
    const int ny  = nb / NX;
    const int ypx = ny >> 3;
    const int bid = blockIdx.x;
    const int by  = (bid & 7) * ypx + (bid >> 3) / NX;
    const int bx  = (bid >> 3) % NX;
    const int rowBase = by * 128, colBase = bx * 128;

    const int tid  = threadIdx.x;
    const int wave = tid >> 6, lane = tid & 63;
    const int wrow = (wave >> 1) * 64, wcol = (wave & 1) * 64;
    const int lr = lane & 15, lq = lane >> 4;

    // staging: thread owns chunks c = tid + 256*i (16 B each); row = c>>3,
    // slot = c&7; source chunk = slot ^ (row&7) (inverse swizzle); LDS dest
    // linear (= wave-uniform base + lane*16, as global_load_lds requires).
    const __bf16* ap[4]; const __bf16* bp[4]; int ld[4];
    #pragma unroll
    for (int i = 0; i < 4; i++) {
        const int c = tid + 256 * i, r = c >> 3, q = (c & 7) ^ (r & 7);
        ap[i] = A + (size_t)(rowBase + r) * K + q * 8;
        bp[i] = W + (size_t)(colBase + r) * K + q * 8;
        ld[i] = c * 8;
    }

    f32x4 acc[4][4] = {};
    const int NS = K >> 6;

    // prologue: stage tiles 0 and 1; wait tile 0 (keep tile 1 in flight)
    STG(0, 0); STG(1, 1);
    asm volatile("s_waitcnt vmcnt(8)"); SBAR;
    __builtin_amdgcn_s_barrier(); SBAR;

    for (int s = 0; s < NS; ++s) {
        const int p = s & 1;
        bf16x8 av[4][2], bv[4][2];
        #pragma unroll
        for (int i = 0; i < 4; i++)
            #pragma unroll
            for (int kk = 0; kk < 2; kk++) {
                const int ra = wrow + i * 16 + lr;
                av[i][kk] = *(const bf16x8*)
                    &As[p * 8192 + ra * 64 + (((kk * 4 + lq) ^ (ra & 7)) * 8)];
                const int rb = wcol + i * 16 + lr;
                bv[i][kk] = *(const bf16x8*)
                    &Bs[p * 8192 + rb * 64 + (((kk * 4 + lq) ^ (rb & 7)) * 8)];
            }
        asm volatile("s_waitcnt lgkmcnt(0)"); SBAR;
        __builtin_amdgcn_s_barrier(); SBAR;   // all waves done reading buf p

        if (s + 2 < NS) STG(s + 2, p);        // refill buf p; flies during MFMA

        __builtin_amdgcn_s_setprio(1);
        #pragma unroll
        for (int kk = 0; kk < 2; kk++)
            #pragma unroll
            for (int i = 0; i < 4; i++)
                #pragma unroll
                for (int j = 0; j < 4; j++)
                    acc[i][j] = __builtin_amdgcn_mfma_f32_16x16x32_bf16(
                        av[i][kk], bv[j][kk], acc[i][j], 0, 0, 0);
        __builtin_amdgcn_s_setprio(0);

        // ensure stage(s+1) landed; keep stage(s+2)'s 8 loads in flight
        if (s + 2 < NS) { asm volatile("s_waitcnt vmcnt(8)"); }
        else            { asm volatile("s_waitcnt vmcnt(0)"); }
        SBAR;
        __builtin_amdgcn_s_barrier(); SBAR;
    }

    #pragma unroll
    for (int i = 0; i < 4; i++)
        #pragma unroll
        for (int j = 0; j < 4; j++) {
            const int col = colBase + wcol + j * 16 + lr;
            #pragma unroll
            for (int r = 0; r < 4; r++) {
                const int row = rowBase + wrow + i * 16 + lq * 4 + r;
                C[(size_t)row * Nc + col] = (__bf16)acc[i][j][r];
            }
        }
}

// ---------------------------------------------------------------------------
// Fused GAT edge-softmax + aggregation (+ optional node head).
// One wave per node n. In-edges = {self, n-1 if same audio}.
// ---------------------------------------------------------------------------
template<int C, bool RELU, bool FUSE_HEAD>
__global__ __launch_bounds__(256)
void agg_fused(const __bf16* __restrict__ h, const __bf16* __restrict__ a_s,
               const __bf16* __restrict__ a_d, const __bf16* __restrict__ bias,
               void* __restrict__ outv,
               const __bf16* __restrict__ Wn, const __bf16* __restrict__ bn,
               const __bf16* __restrict__ Wt, const __bf16* __restrict__ bt,
               void* __restrict__ node_pred, float* __restrict__ logit,
               const int* __restrict__ flag)
{
    constexpr int D = 2 * C;
    constexpr int V = D / 64;
    const int n = blockIdx.x * 4 + (threadIdx.x >> 6);
    const int lane = threadIdx.x & 63;
    const bool have_prev = (n & (NODES_PER_AUDIO - 1)) != 0;
    const size_t np = have_prev ? (size_t)(n - 1) : (size_t)n;
    const int base = lane * V;

    __bf16 h0v[V], h1v[V];
    if constexpr (V == 8) {
        *(int4*)h0v = *(const int4*)(h + (size_t)n * D + base);
        *(int4*)h1v = *(const int4*)(h + np * D + base);
    } else {
        *(int2*)h0v = *(const int2*)(h + (size_t)n * D + base);
        *(int2*)h1v = *(const int2*)(h + np * D + base);
    }

    float ps = 0.f, pd = 0.f, pp = 0.f;
    #pragma unroll
    for (int j = 0; j < V; j++) {
        float av = (float)a_s[base + j], dv = (float)a_d[base + j];
        float x0 = (float)h0v[j], x1 = (float)h1v[j];
        ps += x0 * av; pd += x0 * dv; pp += x1 * av;
    }
    #pragma unroll
    for (int off = 1; off < 32; off <<= 1) {
        ps += __shfl_xor(ps, off, 64);
        pd += __shfl_xor(pd, off, 64);
        pp += __shfl_xor(pp, off, 64);
    }

    float es = ps + pd;  es = es > 0.f ? es : 0.2f * es;
    float a_self = 1.f, a_prev = 0.f;
    if (have_prev) {
        float ep = pp + pd;  ep = ep > 0.f ? ep : 0.2f * ep;
        float m = fmaxf(es, ep);
        float wsx = __expf(es - m), wpx = __expf(ep - m);
        float inv = 1.f / (wsx + wpx);
        a_self = wsx * inv; a_prev = wpx * inv;
    }

    const int cb = (lane & 31) * V;
    float outj[V];
    #pragma unroll
    for (int j = 0; j < V; j++) {
        float p = a_self * (float)h0v[j] + a_prev * (float)h1v[j];
        p = 0.5f * (p + __shfl_xor(p, 32, 64));
        p += (float)bias[cb + j];
        if (RELU) p = fmaxf(p, 0.f);
        outj[j] = p;
    }

    if constexpr (!FUSE_HEAD) {
        if (lane < 32) {
            __bf16 ov[V];
            #pragma unroll
            for (int j = 0; j < V; j++) ov[j] = (__bf16)outj[j];
            if constexpr (V == 8)
                *(int4*)((__bf16*)outv + (size_t)n * C + cb) = *(int4*)ov;
            else
                *(int2*)((__bf16*)outv + (size_t)n * C + cb) = *(int2*)ov;
        }
    } else {
        if (lane < 32)
            *(float4*)((float*)outv + (size_t)n * C + cb) = *(float4*)outj;

        float acc[8];
        #pragma unroll
        for (int k = 0; k < 7; k++) {
            float a = 0.f;
            #pragma unroll
            for (int j = 0; j < V; j++)
                a += outj[j] * (float)Wn[k * C + cb + j];
            acc[k] = a;
        }
        {
            float a = 0.f;
            #pragma unroll
            for (int j = 0; j < V; j++)
                a += outj[j] * (float)Wt[cb + j];
            acc[7] = a;
        }
        #pragma unroll
        for (int off = 1; off < 32; off <<= 1)
            #pragma unroll
            for (int k = 0; k < 8; k++)
                acc[k] += __shfl_xor(acc[k], off, 64);

        if (lane == 0) {
            float lg[7], m = -1e30f;
            #pragma unroll
            for (int k = 0; k < 7; k++) {
                lg[k] = acc[k] + (float)bn[k];
                m = fmaxf(m, lg[k]);
            }
            float s = 0.f;
            #pragma unroll
            for (int k = 0; k < 7; k++) { lg[k] = __expf(lg[k] - m); s += lg[k]; }
            float inv = 1.f / s;
            if (*flag) {
                #pragma unroll
                for (int k = 0; k < 7; k++)
                    ((__bf16*)node_pred)[(size_t)n * 7 + k] = (__bf16)(lg[k] * inv);
            } else {
                #pragma unroll
                for (int k = 0; k < 7; k++)
                    ((float*)node_pred)[(size_t)n * 7 + k] = lg[k] * inv;
            }
            logit[n] = acc[7] + (float)bt[0];
        }
    }
}

// ---------------------------------------------------------------------------
__global__ __launch_bounds__(256)
void audio_stats(const float* __restrict__ logit, float2* __restrict__ stats)
{
    const int b = blockIdx.x;
    const int tid = threadIdx.x;
    __shared__ float red[256];
    const float* lg = logit + b * NODES_PER_AUDIO;

    float m = -1e30f;
    for (int i = tid; i < NODES_PER_AUDIO; i += 256) m = fmaxf(m, lg[i]);
    red[tid] = m; __syncthreads();
    for (int s = 128; s > 0; s >>= 1) {
        if (tid < s) red[tid] = fmaxf(red[tid], red[tid + s]);
        __syncthreads();
    }
    m = red[0]; __syncthreads();

    float s = 0.f;
    for (int i = tid; i < NODES_PER_AUDIO; i += 256) s += __expf(lg[i] - m);
    red[tid] = s; __syncthreads();
    for (int st = 128; st > 0; st >>= 1) {
        if (tid < st) red[tid] += red[tid + st];
        __syncthreads();
    }
    if (tid == 0) stats[b] = make_float2(m, 1.f / red[0]);
}

__global__ __launch_bounds__(256)
void audio_partial(const float* __restrict__ emb, const float* __restrict__ logit,
                   const float2* __restrict__ stats, float* __restrict__ partial)
{
    const int b = blockIdx.x >> 4;
    const int chunk = blockIdx.x & 15;
    const int tid = threadIdx.x;
    const int c = tid & 127, half = tid >> 7;
    const float m = stats[b].x, inv = stats[b].y;
    const float* lg = logit + b * NODES_PER_AUDIO;
    const float* eb = emb + (size_t)b * NODES_PER_AUDIO * 128;

    __shared__ float attbuf[256];
    const int n0 = chunk * CHUNK_NODES + half * (CHUNK_NODES / 2);
    float att = 0.f;
    for (int i = n0; i < n0 + CHUNK_NODES / 2; i++) {
        float w = __expf(lg[i] - m) * inv;
        att += w * eb[(size_t)i * 128 + c];
    }
    attbuf[tid] = att; __syncthreads();
    if (tid < 128)
        partial[(size_t)(b * POOL_CHUNKS + chunk) * 128 + tid] =
            attbuf[tid] + attbuf[tid + 128];
}

__global__ __launch_bounds__(64)
void audio_final(const float* __restrict__ partial, const __bf16* __restrict__ Wa,
                 const __bf16* __restrict__ ba, void* __restrict__ outbase,
                 const int* __restrict__ flag)
{
    const int b = blockIdx.x;
    const int lane = threadIdx.x;
    const float* pb = partial + (size_t)b * POOL_CHUNKS * 128;

    float a0 = 0.f, a1 = 0.f;
    #pragma unroll
    for (int k = 0; k < POOL_CHUNKS; k++) {
        a0 += pb[k * 128 + lane * 2];
        a1 += pb[k * 128 + lane * 2 + 1];
    }
    float p0 = a0 * (float)Wa[lane * 2]       + a1 * (float)Wa[lane * 2 + 1];
    float p1 = a0 * (float)Wa[128 + lane * 2] + a1 * (float)Wa[128 + lane * 2 + 1];
    #pragma unroll
    for (int off = 1; off < 64; off <<= 1) {
        p0 += __shfl_xor(p0, off, 64);
        p1 += __shfl_xor(p1, off, 64);
    }
    if (lane == 0) {
        float r0 = p0 + (float)ba[0];
        float r1 = p1 + (float)ba[1];
        if (*flag) {
            ((__bf16*)outbase)[(size_t)NTOT * 7 + b * 2 + 0] = (__bf16)r0;
            ((__bf16*)outbase)[(size_t)NTOT * 7 + b * 2 + 1] = (__bf16)r1;
        } else {
            ((float*)outbase)[(size_t)NTOT * 7 + b * 2 + 0] = r0;
            ((float*)outbase)[(size_t)NTOT * 7 + b * 2 + 1] = r1;
        }
    }
}

// ---------------------------------------------------------------------------
extern "C" void kernel_launch(void* const* d_in, const int* in_sizes, int n_in,
                              void* d_out, int out_size, void* d_ws, size_t ws_size,
                              hipStream_t stream)
{
    const void* x = d_in[0];
    char* ws = (char*)d_ws;
    const size_t N = NTOT;

    __bf16* h  = (__bf16*)ws;
    size_t off = N * 1024;
    __bf16* h1 = (__bf16*)(ws + off); off += N * 512;
    float* logit = (float*)(ws + off); off += N * 4;
    __bf16* wb = (__bf16*)(ws + off); off += 331008 * 2;
    int* flag = (int*)(ws + off); off += 16;
    float2* stats = (float2*)(ws + off); off += NAUDIO * sizeof(float2);
    float* partial = (float*)(ws + off); off += (size_t)NAUDIO * POOL_CHUNKS * 128 * 4;
    off = (off + 15) & ~(size_t)15;
    __bf16* xb = (__bf16*)(ws + off); off += N * 512 * sizeof(__bf16);
    __bf16* g2 = h;                        // aliases dead h
    float* emb = (float*)(ws + N * 512);   // aliases dead h (2nd half)

    const int O_W1 = 0,      O_W2 = 262144, O_as1 = 327680, O_ad1 = 328192;
    const int O_b1 = 328704, O_as2 = 328960, O_ad2 = 329216, O_b2 = 329472;
    const int O_Wt = 329600, O_bt = 329728, O_Wa = 329736, O_ba = 329992;
    const int O_Wn = 330000, O_bn = 330896;

    W14 w;
    const void* srcs[14] = { d_in[4], d_in[8], d_in[5], d_in[6], d_in[7],
                             d_in[9], d_in[10], d_in[11], d_in[12], d_in[13],
                             d_in[14], d_in[15], d_in[16], d_in[17] };
    const int ns[14]   = { 262144, 65536, 512, 512, 256, 256, 256, 128,
                           128, 1, 256, 2, 896, 7 };
    const int offs[14] = { O_W1, O_W2, O_as1, O_ad1, O_b1, O_as2, O_ad2, O_b2,
                           O_Wt, O_bt, O_Wa, O_ba, O_Wn, O_bn };
    for (int i = 0; i < 14; i++) { w.s[i] = srcs[i]; w.n[i] = ns[i]; w.off[i] = offs[i]; }

    const int nwb = NTOT / 4;

    detect_dtype<<<1, 256, 0, stream>>>((const unsigned*)x, flag);
    convert_weights<<<512, 256, 0, stream>>>(w, flag, wb);
    convert_x<<<2048, 256, 0, stream>>>((const float4*)x, xb, flag);

    // 1) h = x @ W1^T  (pipelined, counted-vmcnt, swizzled)
    gemm_pipe<4><<<4 * (NTOT / 128), 256, 0, stream>>>(
        x, xb, wb + O_W1, h, NTOT, 512, 512, flag);
    // 2) fused GAT layer 1: edge softmax + aggregate + relu -> h1
    agg_fused<256, true, false><<<nwb, 256, 0, stream>>>(
        h, wb + O_as1, wb + O_ad1, wb + O_b1, h1,
        nullptr, nullptr, nullptr, nullptr, nullptr, nullptr, flag);
    // 3) g2 = h1 @ W2^T
    gemm_pipe<2><<<2 * (NTOT / 128), 256, 0, stream>>>(
        h1, h1, wb + O_W2, g2, NTOT, 256, 256, flag);
    // 4) fused GAT layer 2 + node head: emb (f32) + node_pred + logit
    agg_fused<128, false, true><<<nwb, 256, 0, stream>>>(
        g2, wb + O_as2, wb + O_ad2, wb + O_b2, emb,
        wb + O_Wn, wb + O_bn, wb + O_Wt, wb + O_bt, d_out, logit, flag);
    // 5) per-audio softmax pool + audio head
    audio_stats<<<NAUDIO, 256, 0, stream>>>(logit, stats);
    audio_partial<<<NAUDIO * POOL_CHUNKS, 256, 0, stream>>>(emb, logit, stats, partial);
    audio_final<<<NAUDIO, 64, 0, stream>>>(partial, wb + O_Wa, wb + O_ba, d_out, flag);
}